// Round 9
// baseline (657.000 us; speedup 1.0000x reference)
//
#include <hip/hip_runtime.h>
#include <hip/hip_bf16.h>
#include <stdint.h>

#define NTILES 4
#define DMODEL 1024
#define DFF    4096
#define NTOK   16384

typedef __bf16 bf16x8 __attribute__((ext_vector_type(8)));
typedef float  f32x4  __attribute__((ext_vector_type(4)));

__device__ __forceinline__ uint16_t f2bf(float f) {
    union { float f; uint32_t u; } v; v.f = f;
    uint32_t u = v.u;
    uint32_t r = (u + 0x7fffu + ((u >> 16) & 1u)) >> 16;
    return (uint16_t)r;
}

#define STG(gptr, ldsoff) __builtin_amdgcn_global_load_lds( \
    (__attribute__((address_space(1))) void*)(gptr), \
    (__attribute__((address_space(3))) void*)(smem + (ldsoff)), 16, 0, 0)

// ---------------- fused converts: Wup->bf16 (+signature partials) AND Wdown->bf16 ----------------
__global__ void k_convert(const float* __restrict__ Wup, const float* __restrict__ Wdown,
                          uint16_t* __restrict__ wupb, uint16_t* __restrict__ wdownb,
                          double* __restrict__ partial) {
    int e = blockIdx.y, fb = blockIdx.x, tid = threadIdx.x;
    if (fb < 256) {
        const float* src = Wup + (size_t)e * DFF * DMODEL + (size_t)fb * 16 * DMODEL + tid * 4;
        uint16_t*    dst = wupb + (size_t)e * DFF * DMODEL + (size_t)fb * 16 * DMODEL + tid * 4;
        double s0 = 0, s1 = 0, s2 = 0, s3 = 0;
        #pragma unroll 4
        for (int i = 0; i < 16; ++i) {
            float4 v = *(const float4*)(src + (size_t)i * DMODEL);
            ushort4 h;
            h.x = f2bf(v.x); h.y = f2bf(v.y); h.z = f2bf(v.z); h.w = f2bf(v.w);
            *(ushort4*)(dst + (size_t)i * DMODEL) = h;
            s0 += v.x; s1 += v.y; s2 += v.z; s3 += v.w;
        }
        int c = tid * 4;
        double* p = partial + ((size_t)e * DMODEL + c) * 256 + fb;
        p[0 * 256] = s0; p[1 * 256] = s1; p[2 * 256] = s2; p[3 * 256] = s3;
    } else {
        int fb2 = fb - 256;
        const float* src = Wdown + (size_t)e * DMODEL * DFF + (size_t)fb2 * 16384 + tid * 4;
        uint16_t*    dst = wdownb + (size_t)e * DMODEL * DFF + (size_t)fb2 * 16384 + tid * 4;
        #pragma unroll 4
        for (int i = 0; i < 16; ++i) {
            float4 v = *(const float4*)(src + (size_t)i * 1024);
            ushort4 h;
            h.x = f2bf(v.x); h.y = f2bf(v.y); h.z = f2bf(v.z); h.w = f2bf(v.w);
            *(ushort4*)(dst + (size_t)i * 1024) = h;
        }
    }
}

// signature finalize (parallel) + zero expert counts
__global__ void k_sig_final(const double* __restrict__ partial, float* __restrict__ sig,
                            int* __restrict__ counts) {
    int b = blockIdx.x;
    int sub = threadIdx.x >> 5;
    int l32 = threadIdx.x & 31;
    int idx = b * 8 + sub;
    const double* p = partial + (size_t)idx * 256 + l32;
    double s = 0.0;
    #pragma unroll
    for (int i = 0; i < 8; ++i) s += p[i * 32];
    #pragma unroll
    for (int off = 16; off; off >>= 1) s += __shfl_xor(s, off);
    if (l32 == 0) sig[idx] = (s > 0.0) ? 1.0f : ((s < 0.0) ? -1.0f : 0.0f);
    if (b == 0 && threadIdx.x < NTILES) counts[threadIdx.x] = 0;
}

// ---------------- routing: scores, argmax, gate, xb (bf16 copy), buckets ----------------
__global__ void __launch_bounds__(256) k_route(const float* __restrict__ x,
                                               const float* __restrict__ sig,
                                               uint16_t* __restrict__ xb,
                                               float* __restrict__ gate_out,
                                               int* __restrict__ counts,
                                               int* __restrict__ perm) {
    __shared__ float sl[NTILES * DMODEL];
    for (int i = threadIdx.x; i < NTILES * DMODEL; i += 256) sl[i] = sig[i];
    __syncthreads();
    int wave = threadIdx.x >> 6, lane = threadIdx.x & 63;
    int tok = blockIdx.x * 4 + wave;
    const float* xr = x + (size_t)tok * DMODEL;
    float sc[NTILES] = {0.f, 0.f, 0.f, 0.f};
    for (int q = 0; q < 4; ++q) {
        int c = q * 256 + lane * 4;
        float4 xv = *(const float4*)(xr + c);
        #pragma unroll
        for (int t = 0; t < NTILES; ++t) {
            const float* st = sl + t * DMODEL + c;
            sc[t] += xv.x * st[0] + xv.y * st[1] + xv.z * st[2] + xv.w * st[3];
        }
        ushort4 h;
        h.x = f2bf(xv.x); h.y = f2bf(xv.y); h.z = f2bf(xv.z); h.w = f2bf(xv.w);
        *(ushort4*)(xb + (size_t)tok * DMODEL + c) = h;
    }
    #pragma unroll
    for (int t = 0; t < NTILES; ++t)
        for (int off = 32; off; off >>= 1) sc[t] += __shfl_xor(sc[t], off);
    int w = 0; float best = sc[0];
    if (sc[1] > best) { best = sc[1]; w = 1; }
    if (sc[2] > best) { best = sc[2]; w = 2; }
    if (sc[3] > best) { best = sc[3]; w = 3; }
    if (lane < NTILES) gate_out[(size_t)tok * NTILES + lane] = (lane == w) ? 1.0f : 0.0f;
    if (lane == 0) {
        int pos = atomicAdd(&counts[w], 1);
        perm[w * NTOK + pos] = tok;
    }
}

// ---------------- grouped NT GEMM: 128x128 tile, BK=64, 2-slot dbuf, 2 blocks/CU ----------------
// Single-variable vs R8: occupancy. 256 thr = 4 waves (2M x 2N), per-wave 64x64
// (acc[4][4] = 64 VGPR); LDS = 2 x 32KB slots (A 16KB + B 16KB) = 64KB ->
// 2 blocks/CU; __launch_bounds__(256,2) caps VGPR at 256 (no spill; ~155 used).
// Per K-tile: { vmcnt(0); barrier; 16 ds_read; 8 STG(t+1 -> other slot);
// lgkm(0); 32 MFMA }.  Boundary stall hidden by co-resident block (m97/m114).
// Swizzle identical to R2/R8 (rows 128B): phys_in_row = logical ^ ((row&7)<<4).
#define SLOT8 32768

template <int K, bool UP>
__global__ void __launch_bounds__(256, 2)
k_ffn8(const uint16_t* __restrict__ A, const uint16_t* __restrict__ Bw,
       const int* __restrict__ counts, const int* __restrict__ perm,
       uint16_t* __restrict__ hid_out, float* __restrict__ out) {
    constexpr int NOUT = UP ? DFF : DMODEL;
    constexpr int NT = K / 64;
    extern __shared__ char smem[];

    const int e = blockIdx.z;
    const int c0 = counts[0], c1 = counts[1], c2 = counts[2];
    const int cnt = counts[e];
    const int cofs = (e > 0 ? c0 : 0) + (e > 1 ? c1 : 0) + (e > 2 ? c2 : 0);
    const int base = blockIdx.y * 128;
    if (base >= cnt) return;
    const int bn0 = blockIdx.x * 128;
    const int tid = threadIdx.x;
    const int lane = tid & 63, wid = tid >> 6;      // 4 waves
    const int wr = wid >> 1, wc = wid & 1;
    const int* permE = perm + e * NTOK;

    // staging: instr j covers row j*32 + (tid>>3); source granule inverse-swizzled
    const int srow = tid >> 3;                      // 0..31
    const int sg   = (tid & 7) ^ (srow & 7);
    const uint16_t* gA[4];
    const uint16_t* gB[4];
    #pragma unroll
    for (int j = 0; j < 4; ++j) {
        int r  = j * 32 + srow;
        int rr = base + r;
        if constexpr (UP) {
            int tok = permE[(rr < cnt) ? rr : base];
            gA[j] = A + (size_t)tok * K + sg * 8;
        } else {
            gA[j] = A + (size_t)(cofs + rr) * K + sg * 8;
        }
        gB[j] = Bw + ((size_t)e * NOUT + bn0 + r) * K + sg * 8;
    }
    // LDS staging dest bases (wave-uniform; HW adds lane*16); + j*4096 (+ slot)
    const int ldsA = wid * 1024;
    const int ldsB = 16384 + wid * 1024;

    // fragment read offsets (swizzled; row&7 == lane&7 since strides are x8)
    const int Aoff = (wr * 64 + (lane & 15)) * 128;
    const int Boff = 16384 + (wc * 64 + (lane & 15)) * 128;
    const int inr0 = ((lane >> 4) * 16) ^ ((lane & 7) << 4);
    const int inr1 = inr0 ^ 64;

    f32x4 acc[4][4];
    #pragma unroll
    for (int m = 0; m < 4; ++m)
        #pragma unroll
        for (int n = 0; n < 4; ++n) acc[m][n] = (f32x4){0.f, 0.f, 0.f, 0.f};

    // prologue: stage tile 0 -> slot 0
    #pragma unroll
    for (int j = 0; j < 4; ++j) {
        STG(gA[j], ldsA + j * 4096);
        STG(gB[j], ldsB + j * 4096);
    }

    #pragma unroll 1
    for (int t = 0; t < NT; ++t) {
        const char* sp = smem + (t & 1) * SLOT8;
        const int so = ((t + 1) & 1) * SLOT8;
        const bool pre = (t + 1) < NT;

        asm volatile("s_waitcnt vmcnt(0)" ::: "memory");   // tile t's loads landed
        __builtin_amdgcn_sched_barrier(0);
        __builtin_amdgcn_s_barrier();                      // all waves: t ready, t-1 reads done

        bf16x8 aF0[4], bF0[4], aF1[4], bF1[4];
        #pragma unroll
        for (int m = 0; m < 4; ++m) {
            aF0[m] = *(const bf16x8*)(sp + Aoff + m * 2048 + inr0);
            aF1[m] = *(const bf16x8*)(sp + Aoff + m * 2048 + inr1);
        }
        #pragma unroll
        for (int n = 0; n < 4; ++n) {
            bF0[n] = *(const bf16x8*)(sp + Boff + n * 2048 + inr0);
            bF1[n] = *(const bf16x8*)(sp + Boff + n * 2048 + inr1);
        }
        if (pre) {
            #pragma unroll
            for (int j = 0; j < 4; ++j) {
                STG(gA[j] + (t + 1) * 64, so + ldsA + j * 4096);
                STG(gB[j] + (t + 1) * 64, so + ldsB + j * 4096);
            }
        }
        asm volatile("s_waitcnt lgkmcnt(0)" ::: "memory");
        __builtin_amdgcn_sched_barrier(0);
        __builtin_amdgcn_s_setprio(1);
        #pragma unroll
        for (int m = 0; m < 4; ++m)
            #pragma unroll
            for (int n = 0; n < 4; ++n)
                acc[m][n] = __builtin_amdgcn_mfma_f32_16x16x32_bf16(aF0[m], bF0[n], acc[m][n], 0, 0, 0);
        #pragma unroll
        for (int m = 0; m < 4; ++m)
            #pragma unroll
            for (int n = 0; n < 4; ++n)
                acc[m][n] = __builtin_amdgcn_mfma_f32_16x16x32_bf16(aF1[m], bF1[n], acc[m][n], 0, 0, 0);
        __builtin_amdgcn_s_setprio(0);
    }

    // epilogue: r = wr*64 + m*16 + (lane>>4)*4 + i, c = wc*64 + n*16 + (lane&15)
    #pragma unroll
    for (int m = 0; m < 4; ++m) {
        #pragma unroll
        for (int i = 0; i < 4; ++i) {
            int r  = wr * 64 + m * 16 + (lane >> 4) * 4 + i;
            int rr = base + r;
            if (rr < cnt) {
                if constexpr (UP) {
                    uint16_t* hr = hid_out + (size_t)(cofs + rr) * DFF + bn0 + wc * 64;
                    #pragma unroll
                    for (int n = 0; n < 4; ++n) {
                        float v = acc[m][n][i];
                        v = v > 0.f ? v : 0.f;
                        hr[n * 16 + (lane & 15)] = f2bf(v);
                    }
                } else {
                    float* orow = out + (size_t)permE[rr] * DMODEL + bn0 + wc * 64;
                    #pragma unroll
                    for (int n = 0; n < 4; ++n)
                        orow[n * 16 + (lane & 15)] = acc[m][n][i];
                }
            }
        }
    }
}

extern "C" void kernel_launch(void* const* d_in, const int* in_sizes, int n_in,
                              void* d_out, int out_size, void* d_ws, size_t ws_size,
                              hipStream_t stream) {
    const float* x     = (const float*)d_in[0];
    const float* Wup   = (const float*)d_in[1];
    const float* Wdown = (const float*)d_in[2];
    float* out  = (float*)d_out;
    float* gate = out + (size_t)NTOK * DMODEL;

    char* ws = (char*)d_ws;
    size_t off = 0;
    auto alloc = [&](size_t bytes) -> void* {
        void* p = ws + off;
        off += (bytes + 255) & ~(size_t)255;
        return p;
    };
    int*      counts  = (int*)alloc(NTILES * sizeof(int));
    float*    sig     = (float*)alloc((size_t)NTILES * DMODEL * sizeof(float));
    double*   partial = (double*)alloc((size_t)NTILES * DMODEL * 256 * sizeof(double));
    int*      perm    = (int*)alloc((size_t)NTILES * NTOK * sizeof(int));
    uint16_t* xb      = (uint16_t*)alloc((size_t)NTOK * DMODEL * 2);
    uint16_t* wupb    = (uint16_t*)alloc((size_t)NTILES * DFF * DMODEL * 2);
    uint16_t* wdownb  = (uint16_t*)alloc((size_t)NTILES * DMODEL * DFF * 2);
    uint16_t* hidden  = (uint16_t*)alloc(((size_t)NTOK + 1024) * DFF * 2);
    if (off > ws_size) return;

    hipFuncSetAttribute((const void*)&k_ffn8<DMODEL, true>,
                        hipFuncAttributeMaxDynamicSharedMemorySize, 2 * SLOT8);
    hipFuncSetAttribute((const void*)&k_ffn8<DFF, false>,
                        hipFuncAttributeMaxDynamicSharedMemorySize, 2 * SLOT8);

    hipLaunchKernelGGL(k_convert, dim3(512, 4), dim3(256), 0, stream,
                       Wup, Wdown, wupb, wdownb, partial);
    hipLaunchKernelGGL(k_sig_final, dim3(512), dim3(256), 0, stream, partial, sig, counts);
    hipLaunchKernelGGL(k_route, dim3(NTOK / 4), dim3(256), 0, stream,
                       x, sig, xb, gate, counts, perm);
    hipLaunchKernelGGL((k_ffn8<DMODEL, true>), dim3(DFF / 128, NTOK / 128, NTILES),
                       dim3(256), 2 * SLOT8, stream, xb, wupb, counts, perm, hidden, nullptr);
    hipLaunchKernelGGL((k_ffn8<DFF, false>), dim3(DMODEL / 128, NTOK / 128, NTILES),
                       dim3(256), 2 * SLOT8, stream, hidden, wdownb, counts, perm, nullptr, out);
}

// Round 10
// 604.433 us; speedup vs baseline: 1.0870x; 1.0870x over previous
//
#include <hip/hip_runtime.h>
#include <hip/hip_bf16.h>
#include <stdint.h>

#define NTILES 4
#define DMODEL 1024
#define DFF    4096
#define NTOK   16384

typedef __bf16 bf16x8 __attribute__((ext_vector_type(8)));
typedef float  f32x4  __attribute__((ext_vector_type(4)));

__device__ __forceinline__ uint16_t f2bf(float f) {
    union { float f; uint32_t u; } v; v.f = f;
    uint32_t u = v.u;
    uint32_t r = (u + 0x7fffu + ((u >> 16) & 1u)) >> 16;
    return (uint16_t)r;
}

#define STG(gptr, ldsoff) __builtin_amdgcn_global_load_lds( \
    (__attribute__((address_space(1))) void*)(gptr), \
    (__attribute__((address_space(3))) void*)(smem + (ldsoff)), 16, 0, 0)

// ---------------- fused converts: Wup->bf16 (+signature partials) AND Wdown->bf16 ----------------
__global__ void k_convert(const float* __restrict__ Wup, const float* __restrict__ Wdown,
                          uint16_t* __restrict__ wupb, uint16_t* __restrict__ wdownb,
                          double* __restrict__ partial) {
    int e = blockIdx.y, fb = blockIdx.x, tid = threadIdx.x;
    if (fb < 256) {
        const float* src = Wup + (size_t)e * DFF * DMODEL + (size_t)fb * 16 * DMODEL + tid * 4;
        uint16_t*    dst = wupb + (size_t)e * DFF * DMODEL + (size_t)fb * 16 * DMODEL + tid * 4;
        double s0 = 0, s1 = 0, s2 = 0, s3 = 0;
        #pragma unroll 4
        for (int i = 0; i < 16; ++i) {
            float4 v = *(const float4*)(src + (size_t)i * DMODEL);
            ushort4 h;
            h.x = f2bf(v.x); h.y = f2bf(v.y); h.z = f2bf(v.z); h.w = f2bf(v.w);
            *(ushort4*)(dst + (size_t)i * DMODEL) = h;
            s0 += v.x; s1 += v.y; s2 += v.z; s3 += v.w;
        }
        int c = tid * 4;
        double* p = partial + ((size_t)e * DMODEL + c) * 256 + fb;
        p[0 * 256] = s0; p[1 * 256] = s1; p[2 * 256] = s2; p[3 * 256] = s3;
    } else {
        int fb2 = fb - 256;
        const float* src = Wdown + (size_t)e * DMODEL * DFF + (size_t)fb2 * 16384 + tid * 4;
        uint16_t*    dst = wdownb + (size_t)e * DMODEL * DFF + (size_t)fb2 * 16384 + tid * 4;
        #pragma unroll 4
        for (int i = 0; i < 16; ++i) {
            float4 v = *(const float4*)(src + (size_t)i * 1024);
            ushort4 h;
            h.x = f2bf(v.x); h.y = f2bf(v.y); h.z = f2bf(v.z); h.w = f2bf(v.w);
            *(ushort4*)(dst + (size_t)i * 1024) = h;
        }
    }
}

// signature finalize (parallel) + zero expert counts
__global__ void k_sig_final(const double* __restrict__ partial, float* __restrict__ sig,
                            int* __restrict__ counts) {
    int b = blockIdx.x;
    int sub = threadIdx.x >> 5;
    int l32 = threadIdx.x & 31;
    int idx = b * 8 + sub;
    const double* p = partial + (size_t)idx * 256 + l32;
    double s = 0.0;
    #pragma unroll
    for (int i = 0; i < 8; ++i) s += p[i * 32];
    #pragma unroll
    for (int off = 16; off; off >>= 1) s += __shfl_xor(s, off);
    if (l32 == 0) sig[idx] = (s > 0.0) ? 1.0f : ((s < 0.0) ? -1.0f : 0.0f);
    if (b == 0 && threadIdx.x < NTILES) counts[threadIdx.x] = 0;
}

// ---------------- routing: scores, argmax, gate, xb (bf16 copy), buckets ----------------
__global__ void __launch_bounds__(256) k_route(const float* __restrict__ x,
                                               const float* __restrict__ sig,
                                               uint16_t* __restrict__ xb,
                                               float* __restrict__ gate_out,
                                               int* __restrict__ counts,
                                               int* __restrict__ perm) {
    __shared__ float sl[NTILES * DMODEL];
    for (int i = threadIdx.x; i < NTILES * DMODEL; i += 256) sl[i] = sig[i];
    __syncthreads();
    int wave = threadIdx.x >> 6, lane = threadIdx.x & 63;
    int tok = blockIdx.x * 4 + wave;
    const float* xr = x + (size_t)tok * DMODEL;
    float sc[NTILES] = {0.f, 0.f, 0.f, 0.f};
    for (int q = 0; q < 4; ++q) {
        int c = q * 256 + lane * 4;
        float4 xv = *(const float4*)(xr + c);
        #pragma unroll
        for (int t = 0; t < NTILES; ++t) {
            const float* st = sl + t * DMODEL + c;
            sc[t] += xv.x * st[0] + xv.y * st[1] + xv.z * st[2] + xv.w * st[3];
        }
        ushort4 h;
        h.x = f2bf(xv.x); h.y = f2bf(xv.y); h.z = f2bf(xv.z); h.w = f2bf(xv.w);
        *(ushort4*)(xb + (size_t)tok * DMODEL + c) = h;
    }
    #pragma unroll
    for (int t = 0; t < NTILES; ++t)
        for (int off = 32; off; off >>= 1) sc[t] += __shfl_xor(sc[t], off);
    int w = 0; float best = sc[0];
    if (sc[1] > best) { best = sc[1]; w = 1; }
    if (sc[2] > best) { best = sc[2]; w = 2; }
    if (sc[3] > best) { best = sc[3]; w = 3; }
    if (lane < NTILES) gate_out[(size_t)tok * NTILES + lane] = (lane == w) ? 1.0f : 0.0f;
    if (lane == 0) {
        int pos = atomicAdd(&counts[w], 1);
        perm[w * NTOK + pos] = tok;
    }
}

// ---------------- grouped NT GEMM: 128x256 tile, BK=32, 3-slot ring, 2 blocks/CU ----------------
// R2/R8 schedule shape preserved exactly (3-slot ring, 2-tile lookahead, counted
// vmcnt(3) boundary wait, {reads | stage | barrier | lgkm0 | setprio+MFMA |
// vmcnt | barrier} per tile).  Only change vs R8: BK 64->32 so slot = 24KB,
// 3 slots = 72KB -> 2 blocks/CU (16 waves/CU cross-block overlap, m97/m114).
// Swizzle for 64B rows: LDS[row*64 + pg*16] holds logical granule g = pg^((row>>1)&3)
// -> 16-lane frag reads hit every 16B bank-slot exactly twice (2-way = free);
// staging lane-linear: thread tid -> row tid>>2, pg tid&3, source granule
// g = (tid&3) ^ ((tid>>3)&3).
#define SLOT9 24576

template <int K, bool UP>
__global__ void __launch_bounds__(512, 2)
k_ffn9(const uint16_t* __restrict__ A, const uint16_t* __restrict__ Bw,
       const int* __restrict__ counts, const int* __restrict__ perm,
       uint16_t* __restrict__ hid_out, float* __restrict__ out) {
    constexpr int NOUT = UP ? DFF : DMODEL;
    constexpr int NT = K / 32;
    extern __shared__ char smem[];

    const int e = blockIdx.z;
    const int c0 = counts[0], c1 = counts[1], c2 = counts[2];
    const int cnt = counts[e];
    const int cofs = (e > 0 ? c0 : 0) + (e > 1 ? c1 : 0) + (e > 2 ? c2 : 0);
    const int base = blockIdx.y * 128;
    if (base >= cnt) return;
    const int bn0 = blockIdx.x * 256;
    const int tid = threadIdx.x;
    const int lane = tid & 63, wid = tid >> 6;
    const int wr = wid >> 2, wc = wid & 3;        // 2M x 4N, per-wave 64x64
    const int* permE = perm + e * NTOK;

    // ---- staging decode: row = tid>>2, pg = tid&3, logical granule g
    const int srow = tid >> 2;                    // 0..127
    const int sg   = (tid & 3) ^ ((tid >> 3) & 3);
    const uint16_t* gA;
    {
        int rr = base + srow;
        if constexpr (UP) {
            int tok = permE[(rr < cnt) ? rr : base];
            gA = A + (size_t)tok * K + sg * 8;
        } else {
            gA = A + (size_t)(cofs + rr) * K + sg * 8;
        }
    }
    const uint16_t* gB[2];
    #pragma unroll
    for (int j = 0; j < 2; ++j)
        gB[j] = Bw + ((size_t)e * NOUT + bn0 + j * 128 + srow) * K + sg * 8;

    // LDS staging dest bases (wave-uniform; HW adds lane*16): tid*16 within region
    const int ldsA = wid * 1024;                  // A region [0, 8192)
    const int ldsB = 8192 + wid * 1024;           // B region [8192, 24576), + j*8192

    // ---- fragment read offsets: phys_g constant per lane across m/n
    const int pg  = (lane >> 4) ^ (((lane & 15) >> 1) & 3);
    const int Aoff = (wr * 64 + (lane & 15)) * 64 + pg * 16;          // + m*1024
    const int Boff = 8192 + (wc * 64 + (lane & 15)) * 64 + pg * 16;   // + n*1024

    f32x4 acc[4][4];
    #pragma unroll
    for (int m = 0; m < 4; ++m)
        #pragma unroll
        for (int n = 0; n < 4; ++n) acc[m][n] = (f32x4){0.f, 0.f, 0.f, 0.f};

    // prologue: stage tiles 0,1 -> slots 0,1 (3 loads each)
    #pragma unroll
    for (int tt = 0; tt < 2; ++tt) {
        STG(gA + tt * 32,    tt * SLOT9 + ldsA);
        STG(gB[0] + tt * 32, tt * SLOT9 + ldsB);
        STG(gB[1] + tt * 32, tt * SLOT9 + ldsB + 8192);
    }
    asm volatile("s_waitcnt vmcnt(3)" ::: "memory");
    __builtin_amdgcn_sched_barrier(0);
    __builtin_amdgcn_s_barrier();

    int cs = 0;
    #pragma unroll 1
    for (int t = 0; t < NT; ++t) {
        const char* sp = smem + cs * SLOT9;
        const bool pre = (t + 2) < NT;
        const int ss = ((cs == 0) ? 2 : cs - 1) * SLOT9;   // slot of (t+2)%3

        bf16x8 aF[4], bF[4];
        #pragma unroll
        for (int m = 0; m < 4; ++m) aF[m] = *(const bf16x8*)(sp + Aoff + m * 1024);
        #pragma unroll
        for (int n = 0; n < 4; ++n) bF[n] = *(const bf16x8*)(sp + Boff + n * 1024);
        if (pre) {
            STG(gA + (t + 2) * 32,    ss + ldsA);
            STG(gB[0] + (t + 2) * 32, ss + ldsB);
            STG(gB[1] + (t + 2) * 32, ss + ldsB + 8192);
        }
        __builtin_amdgcn_s_barrier();
        asm volatile("s_waitcnt lgkmcnt(0)" ::: "memory");
        __builtin_amdgcn_sched_barrier(0);
        __builtin_amdgcn_s_setprio(1);
        #pragma unroll
        for (int m = 0; m < 4; ++m)
            #pragma unroll
            for (int n = 0; n < 4; ++n)
                acc[m][n] = __builtin_amdgcn_mfma_f32_16x16x32_bf16(aF[m], bF[n], acc[m][n], 0, 0, 0);
        __builtin_amdgcn_s_setprio(0);
        if (pre) { asm volatile("s_waitcnt vmcnt(3)" ::: "memory"); }
        else     { asm volatile("s_waitcnt vmcnt(0)" ::: "memory"); }
        __builtin_amdgcn_sched_barrier(0);
        __builtin_amdgcn_s_barrier();
        cs = (cs == 2) ? 0 : cs + 1;
    }

    // epilogue: r = wr*64 + m*16 + (lane>>4)*4 + i, c = wc*64 + n*16 + (lane&15)
    #pragma unroll
    for (int m = 0; m < 4; ++m) {
        #pragma unroll
        for (int i = 0; i < 4; ++i) {
            int r  = wr * 64 + m * 16 + (lane >> 4) * 4 + i;
            int rr = base + r;
            if (rr < cnt) {
                if constexpr (UP) {
                    uint16_t* hr = hid_out + (size_t)(cofs + rr) * DFF + bn0 + wc * 64;
                    #pragma unroll
                    for (int n = 0; n < 4; ++n) {
                        float v = acc[m][n][i];
                        v = v > 0.f ? v : 0.f;
                        hr[n * 16 + (lane & 15)] = f2bf(v);
                    }
                } else {
                    float* orow = out + (size_t)permE[rr] * DMODEL + bn0 + wc * 64;
                    #pragma unroll
                    for (int n = 0; n < 4; ++n)
                        orow[n * 16 + (lane & 15)] = acc[m][n][i];
                }
            }
        }
    }
}

extern "C" void kernel_launch(void* const* d_in, const int* in_sizes, int n_in,
                              void* d_out, int out_size, void* d_ws, size_t ws_size,
                              hipStream_t stream) {
    const float* x     = (const float*)d_in[0];
    const float* Wup   = (const float*)d_in[1];
    const float* Wdown = (const float*)d_in[2];
    float* out  = (float*)d_out;
    float* gate = out + (size_t)NTOK * DMODEL;

    char* ws = (char*)d_ws;
    size_t off = 0;
    auto alloc = [&](size_t bytes) -> void* {
        void* p = ws + off;
        off += (bytes + 255) & ~(size_t)255;
        return p;
    };
    int*      counts  = (int*)alloc(NTILES * sizeof(int));
    float*    sig     = (float*)alloc((size_t)NTILES * DMODEL * sizeof(float));
    double*   partial = (double*)alloc((size_t)NTILES * DMODEL * 256 * sizeof(double));
    int*      perm    = (int*)alloc((size_t)NTILES * NTOK * sizeof(int));
    uint16_t* xb      = (uint16_t*)alloc((size_t)NTOK * DMODEL * 2);
    uint16_t* wupb    = (uint16_t*)alloc((size_t)NTILES * DFF * DMODEL * 2);
    uint16_t* wdownb  = (uint16_t*)alloc((size_t)NTILES * DMODEL * DFF * 2);
    uint16_t* hidden  = (uint16_t*)alloc(((size_t)NTOK + 1024) * DFF * 2);
    if (off > ws_size) return;

    hipFuncSetAttribute((const void*)&k_ffn9<DMODEL, true>,
                        hipFuncAttributeMaxDynamicSharedMemorySize, 3 * SLOT9);
    hipFuncSetAttribute((const void*)&k_ffn9<DFF, false>,
                        hipFuncAttributeMaxDynamicSharedMemorySize, 3 * SLOT9);

    hipLaunchKernelGGL(k_convert, dim3(512, 4), dim3(256), 0, stream,
                       Wup, Wdown, wupb, wdownb, partial);
    hipLaunchKernelGGL(k_sig_final, dim3(512), dim3(256), 0, stream, partial, sig, counts);
    hipLaunchKernelGGL(k_route, dim3(NTOK / 4), dim3(256), 0, stream,
                       x, sig, xb, gate, counts, perm);
    hipLaunchKernelGGL((k_ffn9<DMODEL, true>), dim3(DFF / 256, NTOK / 128, NTILES),
                       dim3(512), 3 * SLOT9, stream, xb, wupb, counts, perm, hidden, nullptr);
    hipLaunchKernelGGL((k_ffn9<DFF, false>), dim3(DMODEL / 256, NTOK / 128, NTILES),
                       dim3(512), 3 * SLOT9, stream, hidden, wdownb, counts, perm, nullptr, out);
}